// Round 9
// baseline (537.642 us; speedup 1.0000x reference)
//
#include <hip/hip_runtime.h>
#include <stdint.h>

// ---------------------------------------------------------------------------
// PL_MSA round 9: r8 structure, launch_bounds(1024,1).
// Empirical finding (r5/r7/r8): 2nd launch_bounds arg acts as min BLOCKS/CU
// (CUDA semantics) on this hipcc -> (1024,4) forced a 64-VGPR cap and 430 MB
// of spill traffic. (1024,1) -> 128-VGPR cap, 16 waves/CU, spill-free.
// DIM=180 HEADS=6 HD=30 N=256 M=64 B=4 NW=256 BW=1024
// prep -> fused_all (1024 x 1024thr)
// ---------------------------------------------------------------------------

#define NHEADS 6
#define SCALE_Q 0.18257418583505536f  // 30^-0.5

// workspace layout (dword offsets)
#define KVM_OFF   0         // 4 x 360 f32 FiLM scale|shift
#define WCAT_OFF  1440      // [288][192] f16 (rows 0..179 Wq*SCALE, 180..269 Wkv)
#define WPROJ_OFF 29088     // [192][192] f16
#define BCAT_OFF  47520     // 288 f32
#define RPB_OFF   47808     // [6][64][256] f32 gathered bias, TRANSPOSED (h,m,t)

typedef _Float16 f16x8 __attribute__((ext_vector_type(8)));
typedef float    f32x4 __attribute__((ext_vector_type(4)));

__device__ __forceinline__ uint32_t pkf16(float lo, float hi) {
    return __builtin_bit_cast(uint32_t, __builtin_amdgcn_cvt_pkrtz(lo, hi));
}
__device__ __forceinline__ unsigned short f16b(float v) {
    return __builtin_bit_cast(unsigned short, (_Float16)v);
}
__device__ __forceinline__ f32x4 mfma16(f16x8 a, f16x8 b, f32x4 c) {
    return __builtin_amdgcn_mfma_f32_16x16x32_f16(a, b, c, 0, 0, 0);
}

// ---------------------------------------------------------------------------
// prep: FiLM GEMV + weight packing + transposed rel-pos bias gather
// ---------------------------------------------------------------------------
__global__ __launch_bounds__(256) void prep_kernel(
    const float* __restrict__ k_v, const float* __restrict__ W_kernel,
    const float* __restrict__ W_q, const float* __restrict__ b_q,
    const float* __restrict__ W_kv, const float* __restrict__ b_kv,
    const float* __restrict__ W_proj, const float* __restrict__ bias_table,
    const int* __restrict__ rel_index, float* __restrict__ ws)
{
    const int bid = blockIdx.x, tid = threadIdx.x;
    uint32_t* wsd = (uint32_t*)ws;
    if (bid < 6) {
        const int j = bid * 256 + tid;
        if (j < 1440) {
            const int img = j / 360;
            const int o = j - img * 360;
            const float* kr = k_v + img * 256;
            const float* wr = W_kernel + o * 256;
            float s0 = 0.f, s1 = 0.f, s2 = 0.f, s3 = 0.f;
            for (int t = 0; t < 256; t += 4) {
                s0 = fmaf(kr[t + 0], wr[t + 0], s0);
                s1 = fmaf(kr[t + 1], wr[t + 1], s1);
                s2 = fmaf(kr[t + 2], wr[t + 2], s2);
                s3 = fmaf(kr[t + 3], wr[t + 3], s3);
            }
            ws[KVM_OFF + j] = (s0 + s1) + (s2 + s3);
        }
    } else if (bid < 114) {                       // Wcat [288][192]
        const int i = (bid - 6) * 256 + tid;
        if (i < 27648) {
            const int j = i / 96, k0 = (i - j * 96) * 2;
            float v0 = 0.f, v1 = 0.f;
            if (j < 180) {
                if (k0 < 180)     v0 = W_q[j * 180 + k0] * SCALE_Q;
                if (k0 + 1 < 180) v1 = W_q[j * 180 + k0 + 1] * SCALE_Q;
            } else if (j < 270) {
                const int jj = j - 180;
                if (k0 < 180)     v0 = W_kv[jj * 180 + k0];
                if (k0 + 1 < 180) v1 = W_kv[jj * 180 + k0 + 1];
            }
            wsd[WCAT_OFF + i] = pkf16(v0, v1);
        }
    } else if (bid < 186) {                       // Wproj [192][192]
        const int i = (bid - 114) * 256 + tid;
        if (i < 18432) {
            const int j = i / 96, k0 = (i - j * 96) * 2;
            float v0 = (j < 180 && k0 < 180)     ? W_proj[j * 180 + k0]     : 0.f;
            float v1 = (j < 180 && k0 + 1 < 180) ? W_proj[j * 180 + k0 + 1] : 0.f;
            wsd[WPROJ_OFF + i] = pkf16(v0, v1);
        }
    } else if (bid == 186) {                      // bcat
        if (tid < 288) {
            float b = 0.f;
            if (tid < 180)      b = b_q[tid] * SCALE_Q;
            else if (tid < 270) b = b_kv[tid - 180];
            ws[BCAT_OFF + tid] = b;
        }
    } else {                                      // rpb_t [6][64][256] (h,m,t)
        const int i = (bid - 187) * 256 + tid;
        if (i < 98304) {
            const int t = i & 255, m = (i >> 8) & 63, h = i >> 14;
            ws[RPB_OFF + i] = bias_table[rel_index[t * 64 + m] * NHEADS + h];
        }
    }
}

// ---------------------------------------------------------------------------
// fused_all: per-window block, 1024 thr = 16 waves x 16 rows.
// ---------------------------------------------------------------------------
__global__ __launch_bounds__(1024, 1) void fused_all(
    const float* __restrict__ x, const float* __restrict__ mask,
    const float* __restrict__ ws_f, const float* __restrict__ b_proj,
    float* __restrict__ out)
{
    __shared__ __attribute__((aligned(16))) char U[98304];
    char* Kls = U;            // [6][64 m][32 d] swz   (24576 B)
    char* Vt  = U + 24576;    // [6][32 d][64 m] swz   (24576 B)
    char* Scr = U + 49152;    // per-wave 3KB: qsc(1K)|P(2K)  (49152 B)
    char* As  = U;            // proj A-tile [128][384B], aliases Kls|Vt

    const int tid = threadIdx.x;
    const int win = blockIdx.x;
    const int img = win >> 8;
    const int w   = win & 255;
    const int lane = tid & 63, wv = tid >> 6;
    const int lr = lane & 15, lk = lane >> 4;
    const int wrow = wv * 16;

    const uint32_t* wsd = (const uint32_t*)ws_f;
    const _Float16* wcat  = (const _Float16*)(wsd + WCAT_OFF);
    const _Float16* wproj = (const _Float16*)(wsd + WPROJ_OFF);
    const float*    kvs   = ws_f + KVM_OFF + img * 360;
    const float*    bcat  = ws_f + BCAT_OFF;

    // zero Kls d-pads (d=30,31) once
    if (tid < 384) {
        const int h = tid >> 6, mm = tid & 63;
        *(uint32_t*)(Kls + h * 4096 + mm * 64 + ((3u ^ ((mm >> 1) & 3)) << 4) + 12) = 0u;
    }

    const float* xr0 = x + ((size_t)win * 256 + wrow + lr) * 180;

    auto load_af = [&](const float* xrow, int c0) -> f16x8 {
        union { uint32_t u[4]; f16x8 v; } cv;
        if (c0 + 8 <= 180) {
            float4 a  = *(const float4*)(xrow + c0);
            float4 b  = *(const float4*)(xrow + c0 + 4);
            float4 s0 = *(const float4*)(kvs + c0);
            float4 s1 = *(const float4*)(kvs + c0 + 4);
            float4 h0 = *(const float4*)(kvs + 180 + c0);
            float4 h1 = *(const float4*)(kvs + 180 + c0 + 4);
            cv.u[0] = pkf16(fmaf(a.x, s0.x, h0.x), fmaf(a.y, s0.y, h0.y));
            cv.u[1] = pkf16(fmaf(a.z, s0.z, h0.z), fmaf(a.w, s0.w, h0.w));
            cv.u[2] = pkf16(fmaf(b.x, s1.x, h1.x), fmaf(b.y, s1.y, h1.y));
            cv.u[3] = pkf16(fmaf(b.z, s1.z, h1.z), fmaf(b.w, s1.w, h1.w));
        } else if (c0 < 180) {  // c0 == 176
            float4 a  = *(const float4*)(xrow + 176);
            float4 s0 = *(const float4*)(kvs + 176);
            float4 h0 = *(const float4*)(kvs + 356);
            cv.u[0] = pkf16(fmaf(a.x, s0.x, h0.x), fmaf(a.y, s0.y, h0.y));
            cv.u[1] = pkf16(fmaf(a.z, s0.z, h0.z), fmaf(a.w, s0.w, h0.w));
            cv.u[2] = 0u; cv.u[3] = 0u;
        } else {
            cv.u[0] = cv.u[1] = cv.u[2] = cv.u[3] = 0u;
        }
        return cv.v;
    };

    // FiLM'd A-fragments, computed ONCE (x read exactly once)
    f16x8 xa[6];
#pragma unroll
    for (int kk = 0; kk < 6; ++kk)
        xa[kk] = load_af(xr0, kk * 32 + lk * 8);

    auto run6 = [&](int cb, f32x4 (&acc)[6]) {
#pragma unroll
        for (int kk = 0; kk < 6; ++kk) {
#pragma unroll
            for (int nf = 0; nf < 6; ++nf) {
                f16x8 bf = *(const f16x8*)(wcat + (size_t)(cb + nf * 16 + lr) * 192 + kk * 32 + lk * 8);
                acc[nf] = mfma16(xa[kk], bf, acc[nf]);
            }
        }
    };

    // ---- Pass A: kv cols 176..272 -> pooling scatter into Kls/Vt
    {
        f32x4 akv[6];
#pragma unroll
        for (int b = 0; b < 6; ++b) akv[b] = (f32x4){0.f, 0.f, 0.f, 0.f};
        run6(176, akv);
#pragma unroll
        for (int nf = 0; nf < 6; ++nf) {
            const int col = 176 + nf * 16 + lr;
            const int j = col - 180;
            if (j >= 0 && j < 90) {
                const float bb = bcat[col];
                const int d45 = (j < 45) ? j : j - 45;
#pragma unroll
                for (int rr = 0; rr < 4; ++rr) {
                    const int t = wrow + lk * 4 + rr;
                    const int mm = ((t >> 5) << 3) + ((t >> 1) & 7);
                    const int base = ((t >> 4) & 1) * 90 + (t & 1) * 45;
                    const int flat = base + d45;
                    const int h = (flat * 2185) >> 16;
                    const int d = flat - h * 30;
                    const unsigned short hv = f16b(akv[nf][rr] + bb);
                    if (j < 45)
                        *(unsigned short*)(Kls + h * 4096 + mm * 64 +
                            ((((unsigned)d >> 3) ^ ((mm >> 1) & 3)) << 4) + (d & 7) * 2) = hv;
                    else
                        *(unsigned short*)(Vt + h * 4096 + d * 128 +
                            ((((unsigned)mm >> 3) ^ (d & 7)) << 4) + (mm & 7) * 2) = hv;
                }
            }
        }
    }

    // ---- Pass B0/B1: q cols 0..192, packed to f16 register pairs
    uint32_t qp[12][2];
#pragma unroll
    for (int half = 0; half < 2; ++half) {
        f32x4 aq[6];
#pragma unroll
        for (int b = 0; b < 6; ++b) aq[b] = (f32x4){0.f, 0.f, 0.f, 0.f};
        run6(half * 96, aq);
#pragma unroll
        for (int nf = 0; nf < 6; ++nf) {
            const float bb = bcat[half * 96 + nf * 16 + lr];
            qp[half * 6 + nf][0] = pkf16(aq[nf][0] + bb, aq[nf][1] + bb);
            qp[half * 6 + nf][1] = pkf16(aq[nf][2] + bb, aq[nf][3] + bb);
        }
    }

    __syncthreads();   // Kls/Vt complete

    char* scr = Scr + wv * 3072;   // [0,1024) qsc [16][64B] swz
    char* Pw  = scr + 1024;        // [1024,3072) P [16][128B] swz
    const float* rpbt = ws_f + RPB_OFF;

    // zero qsc d-pads (d=30,31) for all 16 rows (NaN guard)
    if (lane < 16)
        *(uint32_t*)(scr + lane * 64 + ((3u ^ ((lane >> 1) & 3)) << 4) + 12) = 0u;

    uint32_t opk[NHEADS][4];       // packed normalized attnout (16 rows)
    const int t0 = wrow + lk * 4;

#pragma unroll
    for (int h = 0; h < NHEADS; ++h) {
        // scatter this head's q slice (cols 30h..30h+30) into qsc
#pragma unroll
        for (int nf = 0; nf < 12; ++nf) {
            if (nf * 16 + 15 >= 30 * h && nf * 16 < 30 * h + 30) {
                const int d = nf * 16 + lr - 30 * h;
                if (d >= 0 && d < 30) {
#pragma unroll
                    for (int rp = 0; rp < 2; ++rp) {
                        const int rL = lk * 4 + rp * 2;  // even row in [0,16)
                        char* p0 = scr + rL * 64 +
                            ((((unsigned)d >> 3) ^ ((rL >> 1) & 3)) << 4) + (d & 7) * 2;
                        const uint32_t q2 = qp[nf][rp];
                        *(unsigned short*)p0        = (unsigned short)(q2 & 0xffffu);
                        *(unsigned short*)(p0 + 64) = (unsigned short)(q2 >> 16);
                    }
                }
            }
        }

        // q A-frag (rows = this wave's 16)
        f16x8 qf = *(const f16x8*)(scr + lr * 64 +
            (((unsigned)lk ^ ((lr >> 1) & 3)) << 4));

        // logits accumulator init: rel-pos bias (vec4) + mask (L1-hot)
        f32x4 sa[4];
#pragma unroll
        for (int mt = 0; mt < 4; ++mt) {
            const int m = mt * 16 + lr;
            const float4 rv = *(const float4*)(rpbt + (((size_t)(h * 64 + m)) << 8) + t0);
            const float* mk = mask + ((((size_t)w << 8) + t0) << 6) + m;
            sa[mt][0] = rv.x + mk[0];
            sa[mt][1] = rv.y + mk[64];
            sa[mt][2] = rv.z + mk[128];
            sa[mt][3] = rv.w + mk[192];
        }

        // QK^T
#pragma unroll
        for (int mt = 0; mt < 4; ++mt) {
            const int mm = mt * 16 + lr;
            f16x8 kf = *(const f16x8*)(Kls + h * 4096 + mm * 64 +
                (((unsigned)lk ^ ((mm >> 1) & 3)) << 4));
            sa[mt] = mfma16(qf, kf, sa[mt]);
        }

        // softmax over m (4 frags x 16 lanes)
        float mx[4], sm[4], inv[4];
#pragma unroll
        for (int rr = 0; rr < 4; ++rr)
            mx[rr] = fmaxf(fmaxf(sa[0][rr], sa[1][rr]), fmaxf(sa[2][rr], sa[3][rr]));
#pragma unroll
        for (int xm = 1; xm < 16; xm <<= 1)
#pragma unroll
            for (int rr = 0; rr < 4; ++rr)
                mx[rr] = fmaxf(mx[rr], __shfl_xor(mx[rr], xm));
#pragma unroll
        for (int mt = 0; mt < 4; ++mt)
#pragma unroll
            for (int rr = 0; rr < 4; ++rr)
                sa[mt][rr] = __expf(sa[mt][rr] - mx[rr]);
#pragma unroll
        for (int rr = 0; rr < 4; ++rr)
            sm[rr] = (sa[0][rr] + sa[1][rr]) + (sa[2][rr] + sa[3][rr]);
#pragma unroll
        for (int xm = 1; xm < 16; xm <<= 1)
#pragma unroll
            for (int rr = 0; rr < 4; ++rr)
                sm[rr] += __shfl_xor(sm[rr], xm);
#pragma unroll
        for (int rr = 0; rr < 4; ++rr) inv[rr] = 1.0f / sm[rr];

        // store unnormalized P [16][64]
#pragma unroll
        for (int mt = 0; mt < 4; ++mt) {
            const int m = mt * 16 + lr;
#pragma unroll
            for (int rr = 0; rr < 4; ++rr) {
                const int r16 = lk * 4 + rr;
                *(unsigned short*)(Pw + r16 * 128 +
                    ((((unsigned)m >> 3) ^ (r16 & 7)) << 4) + (m & 7) * 2) = f16b(sa[mt][rr]);
            }
        }

        // PV
        f32x4 oa[2];
        oa[0] = (f32x4){0.f, 0.f, 0.f, 0.f};
        oa[1] = (f32x4){0.f, 0.f, 0.f, 0.f};
#pragma unroll
        for (int ks = 0; ks < 2; ++ks) {
            f16x8 pa = *(const f16x8*)(Pw + lr * 128 +
                ((((unsigned)(ks * 4 + lk)) ^ (lr & 7)) << 4));
#pragma unroll
            for (int df = 0; df < 2; ++df) {
                const int d = df * 16 + lr;
                f16x8 vb = *(const f16x8*)(Vt + h * 4096 + d * 128 +
                    ((((unsigned)(ks * 4 + lk)) ^ (d & 7)) << 4));
                oa[df] = mfma16(pa, vb, oa[df]);
            }
        }

        // normalize + keep packed in regs for the proj stage
#pragma unroll
        for (int df = 0; df < 2; ++df) {
            opk[h][df * 2 + 0] = pkf16(oa[df][0] * inv[0], oa[df][1] * inv[1]);
            opk[h][df * 2 + 1] = pkf16(oa[df][2] * inv[2], oa[df][3] * inv[3]);
        }
    }

    // ---- proj: stage attnout into dead Kls/Vt region as [128][384B] swz tile
    auto stage16 = [&]() {
        const int rbase = (wv & 7) * 16;
#pragma unroll
        for (int h = 0; h < NHEADS; ++h)
#pragma unroll
            for (int df = 0; df < 2; ++df) {
                const int d = df * 16 + lr;
                if (d < 30) {
                    const int col = h * 30 + d;
#pragma unroll
                    for (int p = 0; p < 2; ++p) {
                        const uint32_t v = opk[h][df * 2 + p];
                        const int r0 = rbase + lk * 4 + p * 2;
                        char* a0 = As + r0 * 384 +
                            ((((unsigned)col >> 3) ^ (r0 & 7)) << 4) + (col & 7) * 2;
                        char* a1 = As + (r0 + 1) * 384 +
                            ((((unsigned)col >> 3) ^ ((r0 + 1) & 7)) << 4) + (col & 7) * 2;
                        *(unsigned short*)a0 = (unsigned short)(v & 0xffffu);
                        *(unsigned short*)a1 = (unsigned short)(v >> 16);
                    }
                }
            }
        // zero K-pad cols 180..191 for this wave's 16 rows
        if (lane < 16) {
            const int r = rbase + lane;
            *(uint2*)(As + r * 384 + ((22u ^ (unsigned)(r & 7)) << 4) + 8) = (uint2){0u, 0u};
            *(uint4*)(As + r * 384 + ((23u ^ (unsigned)(r & 7)) << 4)) = (uint4){0u, 0u, 0u, 0u};
        }
    };

    auto proj_half = [&](int half) {
        const int rblk = wv >> 1, chalf = wv & 1;
        f32x4 acc[6];
#pragma unroll
        for (int nf = 0; nf < 6; ++nf) acc[nf] = (f32x4){0.f, 0.f, 0.f, 0.f};
#pragma unroll
        for (int kk = 0; kk < 6; ++kk) {
            const int r = rblk * 16 + lr;   // 0..127
            f16x8 af = *(const f16x8*)(As + r * 384 +
                ((((unsigned)(kk * 4 + lk)) ^ (r & 7)) << 4));
#pragma unroll
            for (int nf = 0; nf < 6; ++nf) {
                f16x8 bf = *(const f16x8*)(wproj +
                    (size_t)(chalf * 96 + nf * 16 + lr) * 192 + kk * 32 + lk * 8);
                acc[nf] = mfma16(af, bf, acc[nf]);
            }
        }
#pragma unroll
        for (int nf = 0; nf < 6; ++nf) {
            const int j = chalf * 96 + nf * 16 + lr;
            if (j < 180) {
                const float bb = b_proj[j];
                const size_t row = (size_t)win * 256 + half * 128 + rblk * 16 + lk * 4;
#pragma unroll
                for (int rr = 0; rr < 4; ++rr)
                    out[(row + rr) * 180 + j] = acc[nf][rr] + bb;
            }
        }
    };

    __syncthreads();                // all attention done; Kls/Vt dead
    if (wv < 8) stage16();          // rows 0..127
    __syncthreads();
    proj_half(0);
    __syncthreads();
    if (wv >= 8) stage16();         // rows 128..255
    __syncthreads();
    proj_half(1);
}

// ---------------------------------------------------------------------------
extern "C" void kernel_launch(void* const* d_in, const int* in_sizes, int n_in,
                              void* d_out, int out_size, void* d_ws, size_t ws_size,
                              hipStream_t stream)
{
    (void)in_sizes; (void)n_in; (void)out_size; (void)ws_size;
    const float* x          = (const float*)d_in[0];
    const float* k_v        = (const float*)d_in[1];
    const float* mask       = (const float*)d_in[2];
    const float* W_kernel   = (const float*)d_in[3];
    const float* W_q        = (const float*)d_in[4];
    const float* b_q        = (const float*)d_in[5];
    const float* W_kv       = (const float*)d_in[6];
    const float* b_kv       = (const float*)d_in[7];
    const float* bias_table = (const float*)d_in[8];
    const float* W_proj     = (const float*)d_in[9];
    const float* b_proj     = (const float*)d_in[10];
    const int*   rel_index  = (const int*)d_in[11];

    float* ws = (float*)d_ws;

    prep_kernel<<<571, 256, 0, stream>>>(k_v, W_kernel, W_q, b_q, W_kv, b_kv,
                                         W_proj, bias_table, rel_index, ws);
    fused_all<<<1024, 1024, 0, stream>>>(x, mask, ws, b_proj, (float*)d_out);
}

// Round 10
// 437.355 us; speedup vs baseline: 1.2293x; 1.2293x over previous
//
#include <hip/hip_runtime.h>
#include <stdint.h>

// ---------------------------------------------------------------------------
// PL_MSA round 10: 512 thr / 8 waves, launch_bounds(512,2) [honored -> 128 VGPR],
// q routed through ws buf (written in pass B, A-frag loaded directly per head),
// no qsc scatter, LDS 64KB -> 2 blocks/CU. Proj fused (r7 stage/proj verbatim).
// DIM=180 HEADS=6 HD=30 N=256 M=64 B=4 NW=256 BW=1024
// prep -> fused_all (1024 x 512thr)
// ---------------------------------------------------------------------------

#define NHEADS 6
#define SCALE_Q 0.18257418583505536f  // 30^-0.5

// workspace layout (dword offsets)
#define KVM_OFF   0         // 4 x 360 f32 FiLM scale|shift
#define WCAT_OFF  1440      // [288][192] f16 (rows 0..179 Wq*SCALE, 180..269 Wkv)
#define WPROJ_OFF 29088     // [192][192] f16
#define BCAT_OFF  47520     // 288 f32
#define RPB_OFF   47808     // [6][64][256] f32 gathered bias, TRANSPOSED (h,m,t)
#define BUF_DW    146112    // q rows: 262144 x 192 f16 (384B stride), cols 0..179 used

typedef _Float16 f16x8 __attribute__((ext_vector_type(8)));
typedef float    f32x4 __attribute__((ext_vector_type(4)));

__device__ __forceinline__ uint32_t pkf16(float lo, float hi) {
    return __builtin_bit_cast(uint32_t, __builtin_amdgcn_cvt_pkrtz(lo, hi));
}
__device__ __forceinline__ unsigned short f16b(float v) {
    return __builtin_bit_cast(unsigned short, (_Float16)v);
}
__device__ __forceinline__ f32x4 mfma16(f16x8 a, f16x8 b, f32x4 c) {
    return __builtin_amdgcn_mfma_f32_16x16x32_f16(a, b, c, 0, 0, 0);
}

// ---------------------------------------------------------------------------
// prep: FiLM GEMV + weight packing + transposed rel-pos bias gather
// ---------------------------------------------------------------------------
__global__ __launch_bounds__(256) void prep_kernel(
    const float* __restrict__ k_v, const float* __restrict__ W_kernel,
    const float* __restrict__ W_q, const float* __restrict__ b_q,
    const float* __restrict__ W_kv, const float* __restrict__ b_kv,
    const float* __restrict__ W_proj, const float* __restrict__ bias_table,
    const int* __restrict__ rel_index, float* __restrict__ ws)
{
    const int bid = blockIdx.x, tid = threadIdx.x;
    uint32_t* wsd = (uint32_t*)ws;
    if (bid < 6) {
        const int j = bid * 256 + tid;
        if (j < 1440) {
            const int img = j / 360;
            const int o = j - img * 360;
            const float* kr = k_v + img * 256;
            const float* wr = W_kernel + o * 256;
            float s0 = 0.f, s1 = 0.f, s2 = 0.f, s3 = 0.f;
            for (int t = 0; t < 256; t += 4) {
                s0 = fmaf(kr[t + 0], wr[t + 0], s0);
                s1 = fmaf(kr[t + 1], wr[t + 1], s1);
                s2 = fmaf(kr[t + 2], wr[t + 2], s2);
                s3 = fmaf(kr[t + 3], wr[t + 3], s3);
            }
            ws[KVM_OFF + j] = (s0 + s1) + (s2 + s3);
        }
    } else if (bid < 114) {                       // Wcat [288][192]
        const int i = (bid - 6) * 256 + tid;
        if (i < 27648) {
            const int j = i / 96, k0 = (i - j * 96) * 2;
            float v0 = 0.f, v1 = 0.f;
            if (j < 180) {
                if (k0 < 180)     v0 = W_q[j * 180 + k0] * SCALE_Q;
                if (k0 + 1 < 180) v1 = W_q[j * 180 + k0 + 1] * SCALE_Q;
            } else if (j < 270) {
                const int jj = j - 180;
                if (k0 < 180)     v0 = W_kv[jj * 180 + k0];
                if (k0 + 1 < 180) v1 = W_kv[jj * 180 + k0 + 1];
            }
            wsd[WCAT_OFF + i] = pkf16(v0, v1);
        }
    } else if (bid < 186) {                       // Wproj [192][192]
        const int i = (bid - 114) * 256 + tid;
        if (i < 18432) {
            const int j = i / 96, k0 = (i - j * 96) * 2;
            float v0 = (j < 180 && k0 < 180)     ? W_proj[j * 180 + k0]     : 0.f;
            float v1 = (j < 180 && k0 + 1 < 180) ? W_proj[j * 180 + k0 + 1] : 0.f;
            wsd[WPROJ_OFF + i] = pkf16(v0, v1);
        }
    } else if (bid == 186) {                      // bcat
        if (tid < 288) {
            float b = 0.f;
            if (tid < 180)      b = b_q[tid] * SCALE_Q;
            else if (tid < 270) b = b_kv[tid - 180];
            ws[BCAT_OFF + tid] = b;
        }
    } else {                                      // rpb_t [6][64][256] (h,m,t)
        const int i = (bid - 187) * 256 + tid;
        if (i < 98304) {
            const int t = i & 255, m = (i >> 8) & 63, h = i >> 14;
            ws[RPB_OFF + i] = bias_table[rel_index[t * 64 + m] * NHEADS + h];
        }
    }
}

// ---------------------------------------------------------------------------
// fused_all: per-window block, 512 thr = 8 waves x 32 rows.
// ---------------------------------------------------------------------------
__global__ __launch_bounds__(512, 2) void fused_all(
    const float* __restrict__ x, const float* __restrict__ mask,
    const float* __restrict__ ws_f, const float* __restrict__ b_proj,
    _Float16* buf, float* __restrict__ out)
{
    __shared__ __attribute__((aligned(16))) char U[65536];
    char* Kls = U;            // [6][64 m][32 d] swz   (24576 B)
    char* Vt  = U + 24576;    // [6][32 d][64 m] swz   (24576 B)
    char* Pls = U + 49152;    // per-wave 2KB P tile   (16384 B)
    char* As  = U;            // proj A-tile [128][384B], aliases Kls|Vt

    const int tid = threadIdx.x;
    const int win = blockIdx.x;
    const int img = win >> 8;
    const int w   = win & 255;
    const int lane = tid & 63, wv = tid >> 6;
    const int lr = lane & 15, lk = lane >> 4;
    const int wrow = wv * 32;

    const uint32_t* wsd = (const uint32_t*)ws_f;
    const _Float16* wcat  = (const _Float16*)(wsd + WCAT_OFF);
    const _Float16* wproj = (const _Float16*)(wsd + WPROJ_OFF);
    const float*    kvs   = ws_f + KVM_OFF + img * 360;
    const float*    bcat  = ws_f + BCAT_OFF;

    // zero Kls d-pads (d=30,31) once
    if (tid < 384) {
        const int h = tid >> 6, mm = tid & 63;
        *(uint32_t*)(Kls + h * 4096 + mm * 64 + ((3u ^ ((mm >> 1) & 3)) << 4) + 12) = 0u;
    }

    const float* xr0 = x + ((size_t)win * 256 + wrow + lr) * 180;
    const float* xr1 = xr0 + 16 * 180;

    auto load_af = [&](const float* xrow, int c0) -> f16x8 {
        union { uint32_t u[4]; f16x8 v; } cv;
        if (c0 + 8 <= 180) {
            float4 a  = *(const float4*)(xrow + c0);
            float4 b  = *(const float4*)(xrow + c0 + 4);
            float4 s0 = *(const float4*)(kvs + c0);
            float4 s1 = *(const float4*)(kvs + c0 + 4);
            float4 h0 = *(const float4*)(kvs + 180 + c0);
            float4 h1 = *(const float4*)(kvs + 180 + c0 + 4);
            cv.u[0] = pkf16(fmaf(a.x, s0.x, h0.x), fmaf(a.y, s0.y, h0.y));
            cv.u[1] = pkf16(fmaf(a.z, s0.z, h0.z), fmaf(a.w, s0.w, h0.w));
            cv.u[2] = pkf16(fmaf(b.x, s1.x, h1.x), fmaf(b.y, s1.y, h1.y));
            cv.u[3] = pkf16(fmaf(b.z, s1.z, h1.z), fmaf(b.w, s1.w, h1.w));
        } else if (c0 < 180) {  // c0 == 176
            float4 a  = *(const float4*)(xrow + 176);
            float4 s0 = *(const float4*)(kvs + 176);
            float4 h0 = *(const float4*)(kvs + 356);
            cv.u[0] = pkf16(fmaf(a.x, s0.x, h0.x), fmaf(a.y, s0.y, h0.y));
            cv.u[1] = pkf16(fmaf(a.z, s0.z, h0.z), fmaf(a.w, s0.w, h0.w));
            cv.u[2] = 0u; cv.u[3] = 0u;
        } else {
            cv.u[0] = cv.u[1] = cv.u[2] = cv.u[3] = 0u;
        }
        return cv.v;
    };

    // FiLM'd A-fragments, computed ONCE (x read exactly once)
    f16x8 xa[2][6];
#pragma unroll
    for (int kk = 0; kk < 6; ++kk) {
        const int c0 = kk * 32 + lk * 8;
        xa[0][kk] = load_af(xr0, c0);
        xa[1][kk] = load_af(xr1, c0);
    }

    auto run6 = [&](int cb, f32x4 (&acc)[2][6]) {
#pragma unroll
        for (int kk = 0; kk < 6; ++kk) {
#pragma unroll
            for (int nf = 0; nf < 6; ++nf) {
                f16x8 bf = *(const f16x8*)(wcat + (size_t)(cb + nf * 16 + lr) * 192 + kk * 32 + lk * 8);
                acc[0][nf] = mfma16(xa[0][kk], bf, acc[0][nf]);
                acc[1][nf] = mfma16(xa[1][kk], bf, acc[1][nf]);
            }
        }
    };

    // ---- Pass A: kv cols 176..272 -> pooling scatter into Kls/Vt
    {
        f32x4 akv[2][6];
#pragma unroll
        for (int a = 0; a < 2; ++a)
#pragma unroll
            for (int b = 0; b < 6; ++b) akv[a][b] = (f32x4){0.f, 0.f, 0.f, 0.f};
        run6(176, akv);
#pragma unroll
        for (int nf = 0; nf < 6; ++nf) {
            const int col = 176 + nf * 16 + lr;
            const int j = col - 180;
            if (j >= 0 && j < 90) {
                const float bb = bcat[col];
                const int d45 = (j < 45) ? j : j - 45;
#pragma unroll
                for (int mf = 0; mf < 2; ++mf)
#pragma unroll
                    for (int rr = 0; rr < 4; ++rr) {
                        const int t = wrow + mf * 16 + lk * 4 + rr;
                        const int mm = ((t >> 5) << 3) + ((t >> 1) & 7);
                        const int base = ((t >> 4) & 1) * 90 + (t & 1) * 45;
                        const int flat = base + d45;
                        const int h = (flat * 2185) >> 16;
                        const int d = flat - h * 30;
                        const unsigned short hv = f16b(akv[mf][nf][rr] + bb);
                        if (j < 45)
                            *(unsigned short*)(Kls + h * 4096 + mm * 64 +
                                ((((unsigned)d >> 3) ^ ((mm >> 1) & 3)) << 4) + (d & 7) * 2) = hv;
                        else
                            *(unsigned short*)(Vt + h * 4096 + d * 128 +
                                ((((unsigned)mm >> 3) ^ (d & 7)) << 4) + (mm & 7) * 2) = hv;
                    }
            }
        }
    }

    // ---- Pass B0/B1: q cols 0..180 -> straight to buf (burst, no reg/LDS q)
    {
        unsigned short* bw = (unsigned short*)buf;
#pragma unroll
        for (int half = 0; half < 2; ++half) {
            f32x4 aq[2][6];
#pragma unroll
            for (int a = 0; a < 2; ++a)
#pragma unroll
                for (int b = 0; b < 6; ++b) aq[a][b] = (f32x4){0.f, 0.f, 0.f, 0.f};
            run6(half * 96, aq);
#pragma unroll
            for (int nf = 0; nf < 6; ++nf) {
                const int col = half * 96 + nf * 16 + lr;
                if (col < 180) {
                    const float bb = bcat[col];
#pragma unroll
                    for (int mf = 0; mf < 2; ++mf)
#pragma unroll
                        for (int rr = 0; rr < 4; ++rr) {
                            const size_t row = (size_t)win * 256 + wrow + mf * 16 + lk * 4 + rr;
                            bw[row * 192 + col] = f16b(aq[mf][nf][rr] + bb);
                        }
                }
            }
        }
    }

    __syncthreads();   // Kls/Vt complete; q stores drained (vmcnt before barrier)

    char* Pw = Pls + wv * 2048;    // P [16][128B] swz (per qt,h)
    const float* rpbt = ws_f + RPB_OFF;

    uint32_t opk[2][NHEADS][4];    // packed normalized attnout, both qt

#pragma unroll
    for (int qt = 0; qt < 2; ++qt) {
        const int t0 = wrow + qt * 16 + lk * 4;

#pragma unroll
        for (int h = 0; h < NHEADS; ++h) {
            // q A-frag directly from buf: row qt*16+lr, cols 30h+lk*8..+8.
            // lk==3 covers d=30,31 -> zero that dword (NaN-proof; Kls pads also 0)
            union { uint32_t u[4]; f16x8 v; } qc;
            {
                const unsigned short* bq = (const unsigned short*)buf +
                    ((size_t)win * 256 + wrow + qt * 16 + lr) * 192 + h * 30 + lk * 8;
                qc.u[0] = *(const uint32_t*)(bq);
                qc.u[1] = *(const uint32_t*)(bq + 2);
                qc.u[2] = *(const uint32_t*)(bq + 4);
                qc.u[3] = (lk == 3) ? 0u : *(const uint32_t*)(bq + 6);
            }
            const f16x8 qf = qc.v;

            // logits accumulator init: rel-pos bias (vec4) + mask (L1-hot)
            f32x4 sa[4];
#pragma unroll
            for (int mt = 0; mt < 4; ++mt) {
                const int m = mt * 16 + lr;
                const float4 rv = *(const float4*)(rpbt + (((size_t)(h * 64 + m)) << 8) + t0);
                const float* mk = mask + ((((size_t)w << 8) + t0) << 6) + m;
                sa[mt][0] = rv.x + mk[0];
                sa[mt][1] = rv.y + mk[64];
                sa[mt][2] = rv.z + mk[128];
                sa[mt][3] = rv.w + mk[192];
            }

            // QK^T
#pragma unroll
            for (int mt = 0; mt < 4; ++mt) {
                const int mm = mt * 16 + lr;
                f16x8 kf = *(const f16x8*)(Kls + h * 4096 + mm * 64 +
                    (((unsigned)lk ^ ((mm >> 1) & 3)) << 4));
                sa[mt] = mfma16(qf, kf, sa[mt]);
            }

            // softmax over m (4 frags x 16 lanes)
            float mx[4], sm[4], inv[4];
#pragma unroll
            for (int rr = 0; rr < 4; ++rr)
                mx[rr] = fmaxf(fmaxf(sa[0][rr], sa[1][rr]), fmaxf(sa[2][rr], sa[3][rr]));
#pragma unroll
            for (int xm = 1; xm < 16; xm <<= 1)
#pragma unroll
                for (int rr = 0; rr < 4; ++rr)
                    mx[rr] = fmaxf(mx[rr], __shfl_xor(mx[rr], xm));
#pragma unroll
            for (int mt = 0; mt < 4; ++mt)
#pragma unroll
                for (int rr = 0; rr < 4; ++rr)
                    sa[mt][rr] = __expf(sa[mt][rr] - mx[rr]);
#pragma unroll
            for (int rr = 0; rr < 4; ++rr)
                sm[rr] = (sa[0][rr] + sa[1][rr]) + (sa[2][rr] + sa[3][rr]);
#pragma unroll
            for (int xm = 1; xm < 16; xm <<= 1)
#pragma unroll
                for (int rr = 0; rr < 4; ++rr)
                    sm[rr] += __shfl_xor(sm[rr], xm);
#pragma unroll
            for (int rr = 0; rr < 4; ++rr) inv[rr] = 1.0f / sm[rr];

            // store unnormalized P [16][64]
#pragma unroll
            for (int mt = 0; mt < 4; ++mt) {
                const int m = mt * 16 + lr;
#pragma unroll
                for (int rr = 0; rr < 4; ++rr) {
                    const int r16 = lk * 4 + rr;
                    *(unsigned short*)(Pw + r16 * 128 +
                        ((((unsigned)m >> 3) ^ (r16 & 7)) << 4) + (m & 7) * 2) = f16b(sa[mt][rr]);
                }
            }

            // PV
            f32x4 oa[2];
            oa[0] = (f32x4){0.f, 0.f, 0.f, 0.f};
            oa[1] = (f32x4){0.f, 0.f, 0.f, 0.f};
#pragma unroll
            for (int ks = 0; ks < 2; ++ks) {
                f16x8 pa = *(const f16x8*)(Pw + lr * 128 +
                    ((((unsigned)(ks * 4 + lk)) ^ (lr & 7)) << 4));
#pragma unroll
                for (int df = 0; df < 2; ++df) {
                    const int d = df * 16 + lr;
                    f16x8 vb = *(const f16x8*)(Vt + h * 4096 + d * 128 +
                        ((((unsigned)(ks * 4 + lk)) ^ (d & 7)) << 4));
                    oa[df] = mfma16(pa, vb, oa[df]);
                }
            }

            // normalize + keep packed in regs for the proj stage
#pragma unroll
            for (int df = 0; df < 2; ++df) {
                opk[qt][h][df * 2 + 0] = pkf16(oa[df][0] * inv[0], oa[df][1] * inv[1]);
                opk[qt][h][df * 2 + 1] = pkf16(oa[df][2] * inv[2], oa[df][3] * inv[3]);
            }
        }
    }

    // ---- proj: stage attnout into dead Kls/Vt region as [128][384B] swz tile,
    //      two half-tiles; each wave GEMMs 16 rows x 192 cols x K=192.
    auto stage32 = [&]() {
        const int rbase = (wv & 3) * 32;
#pragma unroll
        for (int qt = 0; qt < 2; ++qt)
#pragma unroll
            for (int h = 0; h < NHEADS; ++h)
#pragma unroll
                for (int df = 0; df < 2; ++df) {
                    const int d = df * 16 + lr;
                    if (d < 30) {
                        const int col = h * 30 + d;
#pragma unroll
                        for (int p = 0; p < 2; ++p) {
                            const uint32_t v = opk[qt][h][df * 2 + p];
                            const int r0 = rbase + qt * 16 + lk * 4 + p * 2;
                            char* a0 = As + r0 * 384 +
                                ((((unsigned)col >> 3) ^ (r0 & 7)) << 4) + (col & 7) * 2;
                            char* a1 = As + (r0 + 1) * 384 +
                                ((((unsigned)col >> 3) ^ ((r0 + 1) & 7)) << 4) + (col & 7) * 2;
                            *(unsigned short*)a0 = (unsigned short)(v & 0xffffu);
                            *(unsigned short*)a1 = (unsigned short)(v >> 16);
                        }
                    }
                }
        // zero K-pad cols 180..191 for this wave's 32 rows
        if (lane < 32) {
            const int r = rbase + lane;
            *(uint2*)(As + r * 384 + ((22u ^ (unsigned)(r & 7)) << 4) + 8) = (uint2){0u, 0u};
            *(uint4*)(As + r * 384 + ((23u ^ (unsigned)(r & 7)) << 4)) = (uint4){0u, 0u, 0u, 0u};
        }
    };

    auto proj_half = [&](int half) {
        f32x4 acc[12];
#pragma unroll
        for (int nf = 0; nf < 12; ++nf) acc[nf] = (f32x4){0.f, 0.f, 0.f, 0.f};
#pragma unroll
        for (int kk = 0; kk < 6; ++kk) {
            const int r = wv * 16 + lr;   // 0..127
            f16x8 af = *(const f16x8*)(As + r * 384 +
                ((((unsigned)(kk * 4 + lk)) ^ (r & 7)) << 4));
#pragma unroll
            for (int nf = 0; nf < 12; ++nf) {
                f16x8 bf = *(const f16x8*)(wproj + (size_t)(nf * 16 + lr) * 192 + kk * 32 + lk * 8);
                acc[nf] = mfma16(af, bf, acc[nf]);
            }
        }
#pragma unroll
        for (int nf = 0; nf < 12; ++nf) {
            const int j = nf * 16 + lr;
            if (j < 180) {
                const float bb = b_proj[j];
                const size_t row = (size_t)win * 256 + half * 128 + wv * 16 + lk * 4;
#pragma unroll
                for (int rr = 0; rr < 4; ++rr)
                    out[(row + rr) * 180 + j] = acc[nf][rr] + bb;
            }
        }
    };

    __syncthreads();                // all attention done; Kls/Vt dead
    if (wv < 4) stage32();          // rows 0..127
    __syncthreads();
    proj_half(0);
    __syncthreads();
    if (wv >= 4) stage32();         // rows 128..255
    __syncthreads();
    proj_half(1);
}

// ---------------------------------------------------------------------------
extern "C" void kernel_launch(void* const* d_in, const int* in_sizes, int n_in,
                              void* d_out, int out_size, void* d_ws, size_t ws_size,
                              hipStream_t stream)
{
    (void)in_sizes; (void)n_in; (void)out_size; (void)ws_size;
    const float* x          = (const float*)d_in[0];
    const float* k_v        = (const float*)d_in[1];
    const float* mask       = (const float*)d_in[2];
    const float* W_kernel   = (const float*)d_in[3];
    const float* W_q        = (const float*)d_in[4];
    const float* b_q        = (const float*)d_in[5];
    const float* W_kv       = (const float*)d_in[6];
    const float* b_kv       = (const float*)d_in[7];
    const float* bias_table = (const float*)d_in[8];
    const float* W_proj     = (const float*)d_in[9];
    const float* b_proj     = (const float*)d_in[10];
    const int*   rel_index  = (const int*)d_in[11];

    float* ws = (float*)d_ws;
    _Float16* buf = (_Float16*)((uint32_t*)d_ws + BUF_DW);

    prep_kernel<<<571, 256, 0, stream>>>(k_v, W_kernel, W_q, b_q, W_kv, b_kv,
                                         W_proj, bias_table, rel_index, ws);
    fused_all<<<1024, 512, 0, stream>>>(x, mask, ws, b_proj, buf, (float*)d_out);
}